// Round 5
// baseline (7753.742 us; speedup 1.0000x reference)
//
#include <hip/hip_runtime.h>
#include <cstdint>
#include <cstddef>

typedef unsigned long long u64;

// B=2, A=1000, C=256, R=7, P=49, FC=1024, K_fc1=12544
// out (fp32): [0,8000) bboxes xywh | [8000,10000) objectness | [10000,12000) mask

__device__ __forceinline__ float relu_f(float v){ return fmaxf(v, 0.f); }

// ---------------- transposes ----------------
__global__ void k_feat_t(const float* __restrict__ in, float* __restrict__ out){
  int bp = blockIdx.x;           // b*1024 + yx
  int c  = threadIdx.x;          // 256
  int b  = bp >> 10, yx = bp & 1023;
  out[(size_t)bp*256 + c] = in[((size_t)(b*256 + c))*1024 + yx];
}

__global__ void k_w11t(const float* __restrict__ in, float* __restrict__ out){
  int e = blockIdx.x*256 + threadIdx.x;   // ci*256+co
  int co = e & 255, ci = e >> 8;
  out[e] = in[co*256 + ci];
}

__global__ void k_w33t(const float* __restrict__ in, float* __restrict__ out){
  int e = blockIdx.x*256 + threadIdx.x;   // (tap*256+ci)*256+co
  int co = e & 255;
  int k  = e >> 8;
  int ci = k & 255, tap = k >> 8;
  out[e] = in[(size_t)(co*256 + ci)*9 + tap];
}

// ---------------- fused per-ROI: roi-align + conv1x1 + 2x conv3x3 ----------------
template<int K, int IC>
__device__ __forceinline__ void conv_step(float (&As)[49][260], float (&Bs)[8][256],
    const float* __restrict__ Bw, const float* __restrict__ bias, int t){
  const int cr = t & 31;     // co = cr*8 .. cr*8+7
  const int pr = t >> 5;     // p  = pr + 8j
  float acc[7][8];
  #pragma unroll
  for (int j=0;j<7;j++){
    #pragma unroll
    for (int q=0;q<8;q++) acc[j][q] = 0.f;
  }

  for (int k0 = 0; k0 < K; k0 += 8){
    #pragma unroll
    for (int it=0; it<2; it++){
      int fi = it*256 + t;              // 0..511
      int krow = fi >> 6;               // 0..7
      int c4 = fi & 63;
      *(float4*)&Bs[krow][c4*4] = *(const float4*)&Bw[(size_t)(k0+krow)*256 + c4*4];
    }
    int dy = 0, dx = 0, cbase = k0;
    if (IC){
      int tap = k0 >> 8;                // 8-tile never crosses tap boundary (256%8==0)
      dy = tap/3 - 1; dx = tap%3 - 1;
      cbase = k0 & 255;
    }
    int src[7]; float msk[7];
    #pragma unroll
    for (int j=0;j<7;j++){
      int p = pr + 8*j;
      int py = p/7, px = p%7;
      int yy = py + dy, xx = px + dx;
      bool ok = (p < 49) && (yy >= 0) && (yy < 7) && (xx >= 0) && (xx < 7);
      src[j] = ok ? (yy*7+xx) : 0;
      msk[j] = ok ? 1.f : 0.f;
    }
    __syncthreads();
    #pragma unroll
    for (int kk=0; kk<8; kk++){
      float bv[8];
      *(float4*)&bv[0] = *(const float4*)&Bs[kk][cr*8];
      *(float4*)&bv[4] = *(const float4*)&Bs[kk][cr*8+4];
      #pragma unroll
      for (int j=0;j<7;j++){
        float av = As[src[j]][cbase+kk] * msk[j];
        #pragma unroll
        for (int q=0;q<8;q++) acc[j][q] = fmaf(av, bv[q], acc[j][q]);
      }
    }
    __syncthreads();
  }

  float bb[8];
  *(float4*)&bb[0] = *(const float4*)&bias[cr*8];
  *(float4*)&bb[4] = *(const float4*)&bias[cr*8+4];
  #pragma unroll
  for (int j=0;j<7;j++){
    int p = pr + 8*j;
    if (p < 49){
      float4 o0, o1;
      o0.x = relu_f(acc[j][0]+bb[0]); o0.y = relu_f(acc[j][1]+bb[1]);
      o0.z = relu_f(acc[j][2]+bb[2]); o0.w = relu_f(acc[j][3]+bb[3]);
      o1.x = relu_f(acc[j][4]+bb[4]); o1.y = relu_f(acc[j][5]+bb[5]);
      o1.z = relu_f(acc[j][6]+bb[6]); o1.w = relu_f(acc[j][7]+bb[7]);
      *(float4*)&As[p][cr*8]   = o0;
      *(float4*)&As[p][cr*8+4] = o1;
    }
  }
  __syncthreads();
}

__global__ __launch_bounds__(256) void k_fused_conv(
    const float* __restrict__ featT, const float* __restrict__ prop,
    const float* __restrict__ w11t, const float* __restrict__ b11,
    const float* __restrict__ w1t,  const float* __restrict__ b1,
    const float* __restrict__ w2t,  const float* __restrict__ b2,
    float* __restrict__ X3, int n0){
  __shared__ __align__(16) float As[49][260];   // 50960 B
  __shared__ __align__(16) float Bs[8][256];    // 8192 B
  const int n = n0 + blockIdx.x;
  const int t = threadIdx.x;
  const int b = (n >= 1000) ? 1 : 0;

  const float* pr = prop + n*4;
  float x = pr[0], y = pr[1], w = pr[2], h = pr[3];
  float x1 = x*0.03125f - 0.5f;
  float y1 = y*0.03125f - 0.5f;
  float x2 = (x+w)*0.03125f - 0.5f;
  float y2 = (y+h)*0.03125f - 0.5f;
  float bh = (y2 - y1) / 7.0f;
  float bw = (x2 - x1) / 7.0f;
  const float* fb = featT + (size_t)b*1024*256;
  for (int py = 0; py < 7; py++){
    for (int px = 0; px < 7; px++){
      float acc = 0.f;
      #pragma unroll
      for (int s = 0; s < 4; s++){
        int sy = s >> 1, sx = s & 1;
        float gy = (float)(py*2 + sy);
        float gx = (float)(px*2 + sx);
        float ys = y1 + ((gy + 0.5f) * bh) * 0.5f;
        float xs = x1 + ((gx + 0.5f) * bw) * 0.5f;
        bool valid = (ys > -1.0f) && (ys < 32.0f) && (xs > -1.0f) && (xs < 32.0f);
        float yc = fminf(fmaxf(ys, 0.f), 31.f);
        float xc = fminf(fmaxf(xs, 0.f), 31.f);
        int y0 = (int)floorf(yc), x0 = (int)floorf(xc);
        int y1i = min(y0+1, 31), x1i = min(x0+1, 31);
        float ly = yc - (float)y0, lx = xc - (float)x0;
        float hy = 1.f - ly, hx = 1.f - lx;
        const float* r0 = fb + (size_t)(y0*32)*256;
        const float* r1 = fb + (size_t)(y1i*32)*256;
        float f00 = r0[x0*256 + t],  f01 = r0[x1i*256 + t];
        float f10 = r1[x0*256 + t],  f11 = r1[x1i*256 + t];
        float v = f00*(hy*hx) + f01*(hy*lx) + f10*(ly*hx) + f11*(ly*lx);
        acc += valid ? v : 0.f;
      }
      As[py*7 + px][t] = acc * 0.25f;
    }
  }
  __syncthreads();

  conv_step<256, 0>(As, Bs, w11t, b11, t);
  conv_step<2304,1>(As, Bs, w1t,  b1,  t);
  conv_step<2304,1>(As, Bs, w2t,  b2,  t);

  // X3 row = LOCAL block row; e = co*49 + p matches t.reshape(B,A,-1) order
  for (int i = 0; i < 49; i++){
    int e = i*256 + t;
    int co = e / 49, p = e - co*49;
    X3[(size_t)blockIdx.x*12544 + e] = As[p][co];
  }
}

// ---------------- FC GEMM, B native [N][K]. BM=32 BN=128 BK=32 ----------------
// FIXED: 256 threads = 8x32; thread (r,c) owns rows 4r..4r+3, cols 4c..4c+3.
// (Previous version also used cols 64+4c -> OOB Bs reads + OOB C writes + races.)
__global__ __launch_bounds__(256) void k_gemm_fc_bt(const float* __restrict__ A,
    const float* __restrict__ Bt, const float* __restrict__ bias,
    float* __restrict__ C, int M, int K, int N){
  __shared__ __align__(16) float Ast[32][36];
  __shared__ __align__(16) float Bs[32][128];
  const int t = threadIdx.x;
  const int mt = blockIdx.x, nt = blockIdx.y;
  const int r = t >> 5, c = t & 31;
  float acc[4][4];
  #pragma unroll
  for (int i=0;i<4;i++){
    #pragma unroll
    for (int j=0;j<4;j++) acc[i][j] = 0.f;
  }

  for (int k0 = 0; k0 < K; k0 += 32){
    int gk = k0 + c;
    #pragma unroll
    for (int ms=0; ms<4; ms++){
      int ml = r + ms*8;
      int m = mt*32 + ml;
      Ast[c][ml] = (m < M) ? A[(size_t)m*K + gk] : 0.f;
    }
    #pragma unroll
    for (int it=0; it<4; it++){
      int fi = it*256 + t;               // 0..1023
      int nl = fi & 127, kq = fi >> 7;   // kq 0..7
      int nn = nt*128 + nl;
      float4 v = *(const float4*)&Bt[(size_t)nn*K + k0 + kq*4];
      Bs[kq*4+0][nl] = v.x; Bs[kq*4+1][nl] = v.y;
      Bs[kq*4+2][nl] = v.z; Bs[kq*4+3][nl] = v.w;
    }
    __syncthreads();
    #pragma unroll 8
    for (int kk=0; kk<32; kk++){
      float4 a  = *(const float4*)&Ast[kk][4*r];
      float4 b0 = *(const float4*)&Bs[kk][4*c];
      float av[4] = {a.x,a.y,a.z,a.w};
      float bv[4] = {b0.x,b0.y,b0.z,b0.w};
      #pragma unroll
      for (int i=0;i<4;i++){
        #pragma unroll
        for (int j=0;j<4;j++)
          acc[i][j] = fmaf(av[i], bv[j], acc[i][j]);
      }
    }
    __syncthreads();
  }

  float bv0[4];
  #pragma unroll
  for (int j=0;j<4;j++) bv0[j] = bias[nt*128 + 4*c + j];
  #pragma unroll
  for (int i=0;i<4;i++){
    int gr = mt*32 + 4*r + i;
    if (gr < M){
      float4 o0;
      o0.x = relu_f(acc[i][0]+bv0[0]); o0.y = relu_f(acc[i][1]+bv0[1]);
      o0.z = relu_f(acc[i][2]+bv0[2]); o0.w = relu_f(acc[i][3]+bv0[3]);
      *(float4*)&C[(size_t)gr*N + nt*128 + 4*c] = o0;
    }
  }
}

// ---------------- heads + box regression + clip ----------------
__global__ void k_head(const float* __restrict__ fc2, const float* __restrict__ wobj,
    const float* __restrict__ bobj, const float* __restrict__ wreg, const float* __restrict__ breg,
    const float* __restrict__ prop, float* __restrict__ out){
  int n = blockIdx.x, t = threadIdx.x;
  float s0=0.f, s1=0.f, s2=0.f, s3=0.f, s4=0.f;
  const float* v = fc2 + (size_t)n*1024;
  for (int i = t; i < 1024; i += 256){
    float x = v[i];
    s0 = fmaf(x, wobj[i], s0);
    s1 = fmaf(x, wreg[i], s1);
    s2 = fmaf(x, wreg[1024+i], s2);
    s3 = fmaf(x, wreg[2048+i], s3);
    s4 = fmaf(x, wreg[3072+i], s4);
  }
  #pragma unroll
  for (int off = 32; off >= 1; off >>= 1){
    s0 += __shfl_down(s0, off);
    s1 += __shfl_down(s1, off);
    s2 += __shfl_down(s2, off);
    s3 += __shfl_down(s3, off);
    s4 += __shfl_down(s4, off);
  }
  __shared__ float red[4][5];
  int w = t >> 6, lane = t & 63;
  if (lane == 0){ red[w][0]=s0; red[w][1]=s1; red[w][2]=s2; red[w][3]=s3; red[w][4]=s4; }
  __syncthreads();
  if (t == 0){
    float o0 = red[0][0]+red[1][0]+red[2][0]+red[3][0];
    float o1 = red[0][1]+red[1][1]+red[2][1]+red[3][1];
    float o2 = red[0][2]+red[1][2]+red[2][2]+red[3][2];
    float o3 = red[0][3]+red[1][3]+red[2][3]+red[3][3];
    float o4 = red[0][4]+red[1][4]+red[2][4]+red[3][4];
    float score = 1.f / (1.f + expf(-(o0 + bobj[0])));
    float d0 = (o1 + breg[0]) / 10.f;
    float d1 = (o2 + breg[1]) / 10.f;
    float d2 = (o3 + breg[2]) / 5.f;
    float d3 = (o4 + breg[3]) / 5.f;
    const float* pr = prop + n*4;
    float x = pr[0], y = pr[1], w0 = pr[2], h0 = pr[3];
    float cx = x + 0.5f*w0, cy = y + 0.5f*h0;
    float pw = w0 * expf(d2), ph = h0 * expf(d3);
    float pcx = d0*w0 + cx, pcy = d1*h0 + cy;
    float bx = pcx - 0.5f*pw, by = pcy - 0.5f*ph;
    float ox = fminf(fmaxf(bx, 0.f), 1024.f);
    float oy = fminf(fmaxf(by, 0.f), 1024.f);
    float ow = fminf(fmaxf(pw, 0.f), 1024.f - ox);
    float oh = fminf(fmaxf(ph, 0.f), 1024.f - oy);
    out[n*4+0] = ox; out[n*4+1] = oy; out[n*4+2] = ow; out[n*4+3] = oh;
    out[8000 + n] = score;
  }
}

// ---------------- NMS: stable sort (desc score, asc idx) ----------------
__global__ void k_sort(const float* __restrict__ dout, float* __restrict__ sbox,
                       int* __restrict__ order){
  int b = blockIdx.x, t = threadIdx.x;
  __shared__ u64 key[1024];
  const float* obj = dout + 8000;
  for (int i = t; i < 1024; i += 256){
    u64 k;
    if (i < 1000){
      unsigned bits = __float_as_uint(obj[b*1000+i]);  // sigmoid>0 -> uint order == float order
      k = ((u64)(~bits) << 32) | (unsigned)i;          // asc ~bits == desc score; ties asc idx
    } else {
      k = (0xFFFFFFFFull << 32) | (unsigned)i;
    }
    key[i] = k;
  }
  __syncthreads();
  for (int kk = 2; kk <= 1024; kk <<= 1){
    for (int j = kk >> 1; j > 0; j >>= 1){
      for (int i = t; i < 1024; i += 256){
        int ixj = i ^ j;
        if (ixj > i){
          u64 a = key[i], c2 = key[ixj];
          bool up = ((i & kk) == 0);
          if (up ? (a > c2) : (a < c2)){ key[i] = c2; key[ixj] = a; }
        }
      }
      __syncthreads();
    }
  }
  for (int i = t; i < 1000; i += 256){
    int idx = (int)(key[i] & 0xFFFFFFFFull);
    order[b*1000 + i] = idx;
    const float* bb = dout + (b*1000 + idx)*4;
    float xx = bb[0], yy = bb[1], ww = bb[2], hh = bb[3];
    float4 v; v.x = xx; v.y = yy; v.z = xx + ww; v.w = yy + hh;
    *(float4*)&sbox[(size_t)(b*1000 + i)*4] = v;
  }
}

__global__ void k_mask(const float* __restrict__ sbox, u64* __restrict__ mask){
  int i = blockIdx.x, b = blockIdx.y, t = threadIdx.x;
  float4 bi = *(const float4*)&sbox[(size_t)(b*1000 + i)*4];
  float areaI = fmaxf(bi.z - bi.x, 0.f) * fmaxf(bi.w - bi.y, 0.f);
  int w = t >> 6, lane = t & 63;
  #pragma unroll
  for (int cc = 0; cc < 4; cc++){
    int j = cc*256 + t;
    bool pred = false;
    if (j > i && j < 1000){
      float4 bj = *(const float4*)&sbox[(size_t)(b*1000 + j)*4];
      float areaJ = fmaxf(bj.z - bj.x, 0.f) * fmaxf(bj.w - bj.y, 0.f);
      float ix = fmaxf(bi.x, bj.x), iy = fmaxf(bi.y, bj.y);
      float ax = fminf(bi.z, bj.z), ay = fminf(bi.w, bj.w);
      float iw = fmaxf(ax - ix, 0.f), ih = fmaxf(ay - iy, 0.f);
      float inter = iw * ih;
      float iou = inter / fmaxf(areaI + areaJ - inter, 1e-9f);
      pred = iou > 0.5f;
    }
    u64 ball = __ballot((int)pred);
    if (lane == 0) mask[((size_t)(b*1000 + i))*16 + cc*4 + w] = ball;
  }
}

__global__ void k_scan(const u64* __restrict__ mask, const int* __restrict__ order,
                       const float* __restrict__ dout, float* __restrict__ outmask){
  int b = blockIdx.x, t = threadIdx.x;   // 64 threads
  u64 keepw = ~0ull;
  u64 nxt = (t < 16) ? mask[((size_t)(b*1000))*16 + t] : 0ull;
  for (int i = 0; i < 1000; i++){
    u64 cur = nxt;
    if (t < 16 && i + 1 < 1000) nxt = mask[((size_t)(b*1000 + i + 1))*16 + t];
    int w = i >> 6, bit = i & 63;
    u64 kw = __shfl(keepw, w);
    if ((kw >> bit) & 1ull) keepw &= ~cur;
  }
  __shared__ u64 kws[16];
  if (t < 16) kws[t] = keepw;
  __syncthreads();
  const float* obj = dout + 8000;
  for (int i = t; i < 1000; i += 64){
    int kbit = (int)((kws[i >> 6] >> (i & 63)) & 1ull);
    int orig = order[b*1000 + i];
    float sc = obj[b*1000 + orig];
    outmask[b*1000 + orig] = (kbit && sc > 0.05f) ? 1.0f : 0.0f;
  }
}

// ---------------- launch ----------------
extern "C" void kernel_launch(void* const* d_in, const int* in_sizes, int n_in,
                              void* d_out, int out_size, void* d_ws, size_t ws_size,
                              hipStream_t stream) {
  const float* feature = (const float*)d_in[0];
  const float* prop    = (const float*)d_in[1];
  const float* w11     = (const float*)d_in[2];
  const float* b11     = (const float*)d_in[3];
  const float* w1      = (const float*)d_in[4];
  const float* b1      = (const float*)d_in[5];
  const float* w2      = (const float*)d_in[6];
  const float* b2      = (const float*)d_in[7];
  const float* wf1     = (const float*)d_in[8];
  const float* bf1     = (const float*)d_in[9];
  const float* wf2     = (const float*)d_in[10];
  const float* bf2     = (const float*)d_in[11];
  const float* wobj    = (const float*)d_in[12];
  const float* bobj    = (const float*)d_in[13];
  const float* wreg    = (const float*)d_in[14];
  const float* breg    = (const float*)d_in[15];
  float* out = (float*)d_out;
  float* ws  = (float*)d_ws;

  // ---- ws layout (floats), X3 chunked to fit ws_size ----
  const size_t FIXEDF = 524288 + 65536 + 589824 + 589824 + 2048000 + 2048000
                      + 8000 + 2000 + 64000;   // 5,939,472 floats
  static const int cand[] = {2000, 1000, 500, 250, 125, 64, 32, 16, 8, 4, 2, 1};
  int chunk = 1;
  for (int ci = 0; ci < 12; ci++){
    size_t need = (FIXEDF + (size_t)cand[ci]*12544) * 4;
    if (need <= ws_size){ chunk = cand[ci]; break; }
  }

  float* featT = ws;                         // 524288
  float* w11t  = featT + 524288;             // 65536
  float* w1t   = w11t + 65536;               // 589824
  float* w2t   = w1t + 589824;               // 589824
  float* fc1   = w2t + 589824;               // 2048000
  float* fc2   = fc1 + 2048000;              // 2048000
  float* sbox  = fc2 + 2048000;              // 8000
  int*   order = (int*)(sbox + 8000);        // 2000
  u64*   maskp = (u64*)(sbox + 10000);       // 32000 u64 (64000 floats)
  float* X3c   = sbox + 74000;               // chunk*12544

  k_feat_t<<<2048, 256, 0, stream>>>(feature, featT);
  k_w11t  <<<256,  256, 0, stream>>>(w11, w11t);
  k_w33t  <<<2304, 256, 0, stream>>>(w1, w1t);
  k_w33t  <<<2304, 256, 0, stream>>>(w2, w2t);

  for (int n0 = 0; n0 < 2000; n0 += chunk){
    int cnt = (2000 - n0 < chunk) ? (2000 - n0) : chunk;
    k_fused_conv<<<cnt, 256, 0, stream>>>(featT, prop, w11t, b11, w1t, b1, w2t, b2,
                                          X3c, n0);
    k_gemm_fc_bt<<<dim3((cnt + 31)/32, 8), 256, 0, stream>>>(
        X3c, wf1, bf1, fc1 + (size_t)n0*1024, cnt, 12544, 1024);
  }

  k_gemm_fc_bt<<<dim3(63, 8), 256, 0, stream>>>(fc1, wf2, bf2, fc2, 2000, 1024, 1024);

  k_head<<<2000, 256, 0, stream>>>(fc2, wobj, bobj, wreg, breg, prop, out);

  k_sort<<<2, 256, 0, stream>>>(out, sbox, order);
  k_mask<<<dim3(1000, 2), 256, 0, stream>>>(sbox, maskp);
  k_scan<<<2, 64, 0, stream>>>(maskp, order, out, out + 10000);
}

// Round 7
// 6716.753 us; speedup vs baseline: 1.1544x; 1.1544x over previous
//
#include <hip/hip_runtime.h>
#include <cstdint>
#include <cstddef>

typedef unsigned long long u64;

// B=2, A=1000, C=256, R=7, P=49, FC=1024, K_fc1=12544
// out (fp32): [0,8000) bboxes xywh | [8000,10000) objectness | [10000,12000) mask

__device__ __forceinline__ float relu_f(float v){ return fmaxf(v, 0.f); }

// ---------------- transposes ----------------
__global__ void k_feat_t(const float* __restrict__ in, float* __restrict__ out){
  int bp = blockIdx.x;           // b*1024 + yx
  int c  = threadIdx.x;          // 256
  int b  = bp >> 10, yx = bp & 1023;
  out[(size_t)bp*256 + c] = in[((size_t)(b*256 + c))*1024 + yx];
}

__global__ void k_w11t(const float* __restrict__ in, float* __restrict__ out){
  int e = blockIdx.x*256 + threadIdx.x;   // ci*256+co
  int co = e & 255, ci = e >> 8;
  out[e] = in[co*256 + ci];
}

__global__ void k_w33t(const float* __restrict__ in, float* __restrict__ out){
  int e = blockIdx.x*256 + threadIdx.x;   // (tap*256+ci)*256+co
  int co = e & 255;
  int k  = e >> 8;
  int ci = k & 255, tap = k >> 8;
  out[e] = in[(size_t)(co*256 + ci)*9 + tap];
}

// ---------------- fused per-ROI: roi-align + conv1x1 + 2x conv3x3 ----------------
// 512 threads. Thread (cr = t&31, pr = (t>>5)&7, qh = t>>8) owns
// rows p = pr+8j (j<7, p<49) and cols co = cr + 32*(qh*4+qi), qi<4.
// All LDS element accesses hit bank cr (broadcast or 2-way) -> conflict-free.
template<int K, int IC>
__device__ __forceinline__ void conv_step(float (&As)[49][256], float (&Bs)[8][256],
    const float* __restrict__ Bw, const float* __restrict__ bias, int t){
  const int cr = t & 31;
  const int pr = (t >> 5) & 7;
  const int qh = t >> 8;          // 0 or 1
  float acc[7][4];
  #pragma unroll
  for (int j=0;j<7;j++){
    #pragma unroll
    for (int q=0;q<4;q++) acc[j][q] = 0.f;
  }

  for (int k0 = 0; k0 < K; k0 += 8){
    // stage Bs[8][256] <- Bw[k0..k0+8)[256] : 512 thr x 1 float4 = 2048 floats
    {
      int krow = t >> 6;          // 0..7
      int c4 = t & 63;            // 0..63
      *(float4*)&Bs[krow][c4*4] = *(const float4*)&Bw[(size_t)(k0+krow)*256 + c4*4];
    }
    int dy = 0, dx = 0, cbase = k0;
    if (IC){
      int tap = k0 >> 8;          // 8-tile never crosses tap boundary (256%8==0)
      dy = tap/3 - 1; dx = tap%3 - 1;
      cbase = k0 & 255;
    }
    int src[7]; float msk[7];
    #pragma unroll
    for (int j=0;j<7;j++){
      int p = pr + 8*j;
      int py = p/7, px = p%7;
      int yy = py + dy, xx = px + dx;
      bool ok = (p < 49) && (yy >= 0) && (yy < 7) && (xx >= 0) && (xx < 7);
      src[j] = ok ? (yy*7+xx) : 0;
      msk[j] = ok ? 1.f : 0.f;
    }
    __syncthreads();
    #pragma unroll
    for (int kk=0; kk<8; kk++){
      float bv[4];
      #pragma unroll
      for (int qi=0;qi<4;qi++) bv[qi] = Bs[kk][cr + 32*(qh*4+qi)];
      #pragma unroll
      for (int j=0;j<7;j++){
        float av = As[src[j]][cbase+kk] * msk[j];
        #pragma unroll
        for (int qi=0;qi<4;qi++) acc[j][qi] = fmaf(av, bv[qi], acc[j][qi]);
      }
    }
    __syncthreads();   // all reads done before next Bs stage / writeback
  }

  float bb[4];
  #pragma unroll
  for (int qi=0;qi<4;qi++) bb[qi] = bias[cr + 32*(qh*4+qi)];
  #pragma unroll
  for (int j=0;j<7;j++){
    int p = pr + 8*j;
    if (p < 49){
      #pragma unroll
      for (int qi=0;qi<4;qi++)
        As[p][cr + 32*(qh*4+qi)] = relu_f(acc[j][qi] + bb[qi]);
    }
  }
  __syncthreads();
}

__global__ __launch_bounds__(512, 4) void k_fused_conv(
    const float* __restrict__ featT, const float* __restrict__ prop,
    const float* __restrict__ w11t, const float* __restrict__ b11,
    const float* __restrict__ w1t,  const float* __restrict__ b1,
    const float* __restrict__ w2t,  const float* __restrict__ b2,
    float* __restrict__ X3, int n0){
  __shared__ __align__(16) float As[49][256];   // 50176 B
  __shared__ __align__(16) float Bs[8][256];    // 8192 B  -> 58368 total
  const int n = n0 + blockIdx.x;
  const int t = threadIdx.x;                    // 0..511
  const int b = (n >= 1000) ? 1 : 0;

  // ---- ROI align -> As[p][c] ----
  const float* pr4 = prop + n*4;
  float x = pr4[0], y = pr4[1], w = pr4[2], h = pr4[3];
  float x1 = x*0.03125f - 0.5f;
  float y1 = y*0.03125f - 0.5f;
  float x2 = (x+w)*0.03125f - 0.5f;
  float y2 = (y+h)*0.03125f - 0.5f;
  float bh = (y2 - y1) / 7.0f;
  float bw = (x2 - x1) / 7.0f;
  const float* fb = featT + (size_t)b*1024*256;
  for (int idx = t; idx < 12544; idx += 512){
    int p = idx >> 8;          // 0..48
    int c = idx & 255;
    int py = p / 7, px = p % 7;
    float acc = 0.f;
    #pragma unroll
    for (int s = 0; s < 4; s++){
      int sy = s >> 1, sx = s & 1;
      float gy = (float)(py*2 + sy);
      float gx = (float)(px*2 + sx);
      float ys = y1 + ((gy + 0.5f) * bh) * 0.5f;
      float xs = x1 + ((gx + 0.5f) * bw) * 0.5f;
      bool valid = (ys > -1.0f) && (ys < 32.0f) && (xs > -1.0f) && (xs < 32.0f);
      float yc = fminf(fmaxf(ys, 0.f), 31.f);
      float xc = fminf(fmaxf(xs, 0.f), 31.f);
      int y0 = (int)floorf(yc), x0 = (int)floorf(xc);
      int y1i = min(y0+1, 31), x1i = min(x0+1, 31);
      float ly = yc - (float)y0, lx = xc - (float)x0;
      float hy = 1.f - ly, hx = 1.f - lx;
      const float* r0 = fb + (size_t)(y0*32)*256;
      const float* r1 = fb + (size_t)(y1i*32)*256;
      float f00 = r0[x0*256 + c],  f01 = r0[x1i*256 + c];
      float f10 = r1[x0*256 + c],  f11 = r1[x1i*256 + c];
      float v = f00*(hy*hx) + f01*(hy*lx) + f10*(ly*hx) + f11*(ly*lx);
      acc += valid ? v : 0.f;
    }
    As[p][c] = acc * 0.25f;
  }
  __syncthreads();

  conv_step<256, 0>(As, Bs, w11t, b11, t);
  conv_step<2304,1>(As, Bs, w1t,  b1,  t);
  conv_step<2304,1>(As, Bs, w2t,  b2,  t);

  // ---- write X3[e], e = co*49 + p (matches t.reshape(B,A,-1) order) ----
  #pragma unroll
  for (int i = 0; i < 25; i++){
    int e = i*512 + t;
    if (e < 12544){
      int co = e / 49, p = e - co*49;
      X3[(size_t)blockIdx.x*12544 + e] = As[p][co];
    }
  }
}

// ---------------- FC GEMM, B native [N][K]. BM=32 BN=128 BK=32 ----------------
// 256 threads = 8x32; thread (r,c) owns rows 4r..4r+3, cols 4c..4c+3.
__global__ __launch_bounds__(256) void k_gemm_fc_bt(const float* __restrict__ A,
    const float* __restrict__ Bt, const float* __restrict__ bias,
    float* __restrict__ C, int M, int K, int N){
  __shared__ __align__(16) float Ast[32][36];
  __shared__ __align__(16) float Bs[32][128];
  const int t = threadIdx.x;
  const int mt = blockIdx.x, nt = blockIdx.y;
  const int r = t >> 5, c = t & 31;
  float acc[4][4];
  #pragma unroll
  for (int i=0;i<4;i++){
    #pragma unroll
    for (int j=0;j<4;j++) acc[i][j] = 0.f;
  }

  for (int k0 = 0; k0 < K; k0 += 32){
    int gk = k0 + c;
    #pragma unroll
    for (int ms=0; ms<4; ms++){
      int ml = r + ms*8;
      int m = mt*32 + ml;
      Ast[c][ml] = (m < M) ? A[(size_t)m*K + gk] : 0.f;
    }
    #pragma unroll
    for (int it=0; it<4; it++){
      int fi = it*256 + t;               // 0..1023
      int nl = fi & 127, kq = fi >> 7;   // kq 0..7
      int nn = nt*128 + nl;
      float4 v = *(const float4*)&Bt[(size_t)nn*K + k0 + kq*4];
      Bs[kq*4+0][nl] = v.x; Bs[kq*4+1][nl] = v.y;
      Bs[kq*4+2][nl] = v.z; Bs[kq*4+3][nl] = v.w;
    }
    __syncthreads();
    #pragma unroll 8
    for (int kk=0; kk<32; kk++){
      float4 a  = *(const float4*)&Ast[kk][4*r];
      float4 b0 = *(const float4*)&Bs[kk][4*c];
      float av[4] = {a.x,a.y,a.z,a.w};
      float bv[4] = {b0.x,b0.y,b0.z,b0.w};
      #pragma unroll
      for (int i=0;i<4;i++){
        #pragma unroll
        for (int j=0;j<4;j++)
          acc[i][j] = fmaf(av[i], bv[j], acc[i][j]);
      }
    }
    __syncthreads();
  }

  float bv0[4];
  #pragma unroll
  for (int j=0;j<4;j++) bv0[j] = bias[nt*128 + 4*c + j];
  #pragma unroll
  for (int i=0;i<4;i++){
    int gr = mt*32 + 4*r + i;
    if (gr < M){
      float4 o0;
      o0.x = relu_f(acc[i][0]+bv0[0]); o0.y = relu_f(acc[i][1]+bv0[1]);
      o0.z = relu_f(acc[i][2]+bv0[2]); o0.w = relu_f(acc[i][3]+bv0[3]);
      *(float4*)&C[(size_t)gr*N + nt*128 + 4*c] = o0;
    }
  }
}

// ---------------- heads + box regression + clip ----------------
__global__ void k_head(const float* __restrict__ fc2, const float* __restrict__ wobj,
    const float* __restrict__ bobj, const float* __restrict__ wreg, const float* __restrict__ breg,
    const float* __restrict__ prop, float* __restrict__ out){
  int n = blockIdx.x, t = threadIdx.x;
  float s0=0.f, s1=0.f, s2=0.f, s3=0.f, s4=0.f;
  const float* v = fc2 + (size_t)n*1024;
  for (int i = t; i < 1024; i += 256){
    float x = v[i];
    s0 = fmaf(x, wobj[i], s0);
    s1 = fmaf(x, wreg[i], s1);
    s2 = fmaf(x, wreg[1024+i], s2);
    s3 = fmaf(x, wreg[2048+i], s3);
    s4 = fmaf(x, wreg[3072+i], s4);
  }
  #pragma unroll
  for (int off = 32; off >= 1; off >>= 1){
    s0 += __shfl_down(s0, off);
    s1 += __shfl_down(s1, off);
    s2 += __shfl_down(s2, off);
    s3 += __shfl_down(s3, off);
    s4 += __shfl_down(s4, off);
  }
  __shared__ float red[4][5];
  int w = t >> 6, lane = t & 63;
  if (lane == 0){ red[w][0]=s0; red[w][1]=s1; red[w][2]=s2; red[w][3]=s3; red[w][4]=s4; }
  __syncthreads();
  if (t == 0){
    float o0 = red[0][0]+red[1][0]+red[2][0]+red[3][0];
    float o1 = red[0][1]+red[1][1]+red[2][1]+red[3][1];
    float o2 = red[0][2]+red[1][2]+red[2][2]+red[3][2];
    float o3 = red[0][3]+red[1][3]+red[2][3]+red[3][3];
    float o4 = red[0][4]+red[1][4]+red[2][4]+red[3][4];
    float score = 1.f / (1.f + expf(-(o0 + bobj[0])));
    float d0 = (o1 + breg[0]) / 10.f;
    float d1 = (o2 + breg[1]) / 10.f;
    float d2 = (o3 + breg[2]) / 5.f;
    float d3 = (o4 + breg[3]) / 5.f;
    const float* pr = prop + n*4;
    float x = pr[0], y = pr[1], w0 = pr[2], h0 = pr[3];
    float cx = x + 0.5f*w0, cy = y + 0.5f*h0;
    float pw = w0 * expf(d2), ph = h0 * expf(d3);
    float pcx = d0*w0 + cx, pcy = d1*h0 + cy;
    float bx = pcx - 0.5f*pw, by = pcy - 0.5f*ph;
    float ox = fminf(fmaxf(bx, 0.f), 1024.f);
    float oy = fminf(fmaxf(by, 0.f), 1024.f);
    float ow = fminf(fmaxf(pw, 0.f), 1024.f - ox);
    float oh = fminf(fmaxf(ph, 0.f), 1024.f - oy);
    out[n*4+0] = ox; out[n*4+1] = oy; out[n*4+2] = ow; out[n*4+3] = oh;
    out[8000 + n] = score;
  }
}

// ---------------- NMS: stable sort (desc score, asc idx) ----------------
__global__ void k_sort(const float* __restrict__ dout, float* __restrict__ sbox,
                       int* __restrict__ order){
  int b = blockIdx.x, t = threadIdx.x;
  __shared__ u64 key[1024];
  const float* obj = dout + 8000;
  for (int i = t; i < 1024; i += 256){
    u64 k;
    if (i < 1000){
      unsigned bits = __float_as_uint(obj[b*1000+i]);  // sigmoid>0 -> uint order == float order
      k = ((u64)(~bits) << 32) | (unsigned)i;          // asc ~bits == desc score; ties asc idx
    } else {
      k = (0xFFFFFFFFull << 32) | (unsigned)i;
    }
    key[i] = k;
  }
  __syncthreads();
  for (int kk = 2; kk <= 1024; kk <<= 1){
    for (int j = kk >> 1; j > 0; j >>= 1){
      for (int i = t; i < 1024; i += 256){
        int ixj = i ^ j;
        if (ixj > i){
          u64 a = key[i], c2 = key[ixj];
          bool up = ((i & kk) == 0);
          if (up ? (a > c2) : (a < c2)){ key[i] = c2; key[ixj] = a; }
        }
      }
      __syncthreads();
    }
  }
  for (int i = t; i < 1000; i += 256){
    int idx = (int)(key[i] & 0xFFFFFFFFull);
    order[b*1000 + i] = idx;
    const float* bb = dout + (b*1000 + idx)*4;
    float xx = bb[0], yy = bb[1], ww = bb[2], hh = bb[3];
    float4 v; v.x = xx; v.y = yy; v.z = xx + ww; v.w = yy + hh;
    *(float4*)&sbox[(size_t)(b*1000 + i)*4] = v;
  }
}

__global__ void k_mask(const float* __restrict__ sbox, u64* __restrict__ mask){
  int i = blockIdx.x, b = blockIdx.y, t = threadIdx.x;
  float4 bi = *(const float4*)&sbox[(size_t)(b*1000 + i)*4];
  float areaI = fmaxf(bi.z - bi.x, 0.f) * fmaxf(bi.w - bi.y, 0.f);
  int w = t >> 6, lane = t & 63;
  #pragma unroll
  for (int cc = 0; cc < 4; cc++){
    int j = cc*256 + t;
    bool pred = false;
    if (j > i && j < 1000){
      float4 bj = *(const float4*)&sbox[(size_t)(b*1000 + j)*4];
      float areaJ = fmaxf(bj.z - bj.x, 0.f) * fmaxf(bj.w - bj.y, 0.f);
      float ix = fmaxf(bi.x, bj.x), iy = fmaxf(bi.y, bj.y);
      float ax = fminf(bi.z, bj.z), ay = fminf(bi.w, bj.w);
      float iw = fmaxf(ax - ix, 0.f), ih = fmaxf(ay - iy, 0.f);
      float inter = iw * ih;
      float iou = inter / fmaxf(areaI + areaJ - inter, 1e-9f);
      pred = iou > 0.5f;
    }
    u64 ball = __ballot((int)pred);
    if (lane == 0) mask[((size_t)(b*1000 + i))*16 + cc*4 + w] = ball;
  }
}

__global__ void k_scan(const u64* __restrict__ mask, const int* __restrict__ order,
                       const float* __restrict__ dout, float* __restrict__ outmask){
  int b = blockIdx.x, t = threadIdx.x;   // 64 threads
  u64 keepw = ~0ull;
  u64 nxt = (t < 16) ? mask[((size_t)(b*1000))*16 + t] : 0ull;
  for (int i = 0; i < 1000; i++){
    u64 cur = nxt;
    if (t < 16 && i + 1 < 1000) nxt = mask[((size_t)(b*1000 + i + 1))*16 + t];
    int w = i >> 6, bit = i & 63;
    u64 kw = __shfl(keepw, w);
    if ((kw >> bit) & 1ull) keepw &= ~cur;
  }
  __shared__ u64 kws[16];
  if (t < 16) kws[t] = keepw;
  __syncthreads();
  const float* obj = dout + 8000;
  for (int i = t; i < 1000; i += 64){
    int kbit = (int)((kws[i >> 6] >> (i & 63)) & 1ull);
    int orig = order[b*1000 + i];
    float sc = obj[b*1000 + orig];
    outmask[b*1000 + orig] = (kbit && sc > 0.05f) ? 1.0f : 0.0f;
  }
}

// ---------------- launch ----------------
extern "C" void kernel_launch(void* const* d_in, const int* in_sizes, int n_in,
                              void* d_out, int out_size, void* d_ws, size_t ws_size,
                              hipStream_t stream) {
  const float* feature = (const float*)d_in[0];
  const float* prop    = (const float*)d_in[1];
  const float* w11     = (const float*)d_in[2];
  const float* b11     = (const float*)d_in[3];
  const float* w1      = (const float*)d_in[4];
  const float* b1      = (const float*)d_in[5];
  const float* w2      = (const float*)d_in[6];
  const float* b2      = (const float*)d_in[7];
  const float* wf1     = (const float*)d_in[8];
  const float* bf1     = (const float*)d_in[9];
  const float* wf2     = (const float*)d_in[10];
  const float* bf2     = (const float*)d_in[11];
  const float* wobj    = (const float*)d_in[12];
  const float* bobj    = (const float*)d_in[13];
  const float* wreg    = (const float*)d_in[14];
  const float* breg    = (const float*)d_in[15];
  float* out = (float*)d_out;
  float* ws  = (float*)d_ws;

  // ---- ws layout (floats), X3 chunked to fit ws_size ----
  const size_t FIXEDF = 524288 + 65536 + 589824 + 589824 + 2048000 + 2048000
                      + 8000 + 2000 + 64000;   // 5,939,472 floats
  static const int cand[] = {2000, 1000, 500, 250, 125, 64, 32, 16, 8, 4, 2, 1};
  int chunk = 1;
  for (int ci = 0; ci < 12; ci++){
    size_t need = (FIXEDF + (size_t)cand[ci]*12544) * 4;
    if (need <= ws_size){ chunk = cand[ci]; break; }
  }

  float* featT = ws;                         // 524288
  float* w11t  = featT + 524288;             // 65536
  float* w1t   = w11t + 65536;               // 589824
  float* w2t   = w1t + 589824;               // 589824
  float* fc1   = w2t + 589824;               // 2048000
  float* fc2   = fc1 + 2048000;              // 2048000
  float* sbox  = fc2 + 2048000;              // 8000
  int*   order = (int*)(sbox + 8000);        // 2000
  u64*   maskp = (u64*)(sbox + 10000);       // 32000 u64 (64000 floats)
  float* X3c   = sbox + 74000;               // chunk*12544

  k_feat_t<<<2048, 256, 0, stream>>>(feature, featT);
  k_w11t  <<<256,  256, 0, stream>>>(w11, w11t);
  k_w33t  <<<2304, 256, 0, stream>>>(w1, w1t);
  k_w33t  <<<2304, 256, 0, stream>>>(w2, w2t);

  for (int n0 = 0; n0 < 2000; n0 += chunk){
    int cnt = (2000 - n0 < chunk) ? (2000 - n0) : chunk;
    k_fused_conv<<<cnt, 512, 0, stream>>>(featT, prop, w11t, b11, w1t, b1, w2t, b2,
                                          X3c, n0);
    k_gemm_fc_bt<<<dim3((cnt + 31)/32, 8), 256, 0, stream>>>(
        X3c, wf1, bf1, fc1 + (size_t)n0*1024, cnt, 12544, 1024);
  }

  k_gemm_fc_bt<<<dim3(63, 8), 256, 0, stream>>>(fc1, wf2, bf2, fc2, 2000, 1024, 1024);

  k_head<<<2000, 256, 0, stream>>>(fc2, wobj, bobj, wreg, breg, prop, out);

  k_sort<<<2, 256, 0, stream>>>(out, sbox, order);
  k_mask<<<dim3(1000, 2), 256, 0, stream>>>(sbox, maskp);
  k_scan<<<2, 64, 0, stream>>>(maskp, order, out, out + 10000);
}

// Round 8
// 6131.603 us; speedup vs baseline: 1.2646x; 1.0954x over previous
//
#include <hip/hip_runtime.h>
#include <cstdint>
#include <cstddef>

typedef unsigned long long u64;

// B=2, A=1000, C=256, R=7, P=49, FC=1024, K_fc1=12544
// out (fp32): [0,8000) bboxes xywh | [8000,10000) objectness | [10000,12000) mask

__device__ __forceinline__ float relu_f(float v){ return fmaxf(v, 0.f); }

// ---------------- transposes ----------------
__global__ void k_feat_t(const float* __restrict__ in, float* __restrict__ out){
  int bp = blockIdx.x;           // b*1024 + yx
  int c  = threadIdx.x;          // 256
  int b  = bp >> 10, yx = bp & 1023;
  out[(size_t)bp*256 + c] = in[((size_t)(b*256 + c))*1024 + yx];
}

__global__ void k_w11t(const float* __restrict__ in, float* __restrict__ out){
  int e = blockIdx.x*256 + threadIdx.x;   // ci*256+co
  int co = e & 255, ci = e >> 8;
  out[e] = in[co*256 + ci];
}

__global__ void k_w33t(const float* __restrict__ in, float* __restrict__ out){
  int e = blockIdx.x*256 + threadIdx.x;   // (tap*256+ci)*256+co
  int co = e & 255;
  int k  = e >> 8;
  int ci = k & 255, tap = k >> 8;
  out[e] = in[(size_t)(co*256 + ci)*9 + tap];
}

// ---------------- fused per-ROI conv chain, x-padded LDS layout ----------------
// As[64][256]: interior row = py*9 + px + 1 (py,px in [0,7)); slots py*9+0 / py*9+8
// are zeroed x-pads; row 63 is the zero row (y-OOB + invalid p). Inner loop has
// NO masks/divmod: 28 FMA + 11 scalar ds_read per kk, all LDS accesses bank-aligned.
template<int K, int IC>
__device__ __forceinline__ void conv_step(float (&As)[64][256], float (&Bs)[8][256],
    const float* __restrict__ Bw, const float* __restrict__ bias, int t){
  const int cr = t & 31;          // column lane
  const int pr = (t >> 5) & 7;    // row group: rows p = pr + 8j
  const int qh = t >> 8;          // 0/1: columns co = cr + 32*(qh*4+qi)

  int pyv[7], rowb[7];
  #pragma unroll
  for (int j = 0; j < 7; j++){
    int p = pr + 8*j;
    int pyj = p / 7, pxj = p - pyj*7;
    bool v = (p < 49);
    pyv[j]  = v ? pyj : 99;
    rowb[j] = v ? (pyj*9 + pxj + 1) : 63;
  }

  float acc[7][4];
  #pragma unroll
  for (int j=0;j<7;j++){
    #pragma unroll
    for (int q=0;q<4;q++) acc[j][q] = 0.f;
  }

  for (int k0 = 0; k0 < K; k0 += 8){
    // stage Bs[8][256] <- Bw[k0..k0+8)[256] : 512 thr x 1 float4
    {
      int krow = t >> 6;          // 0..7
      int c4 = t & 63;            // 0..63
      *(float4*)&Bs[krow][c4*4] = *(const float4*)&Bw[(size_t)(k0+krow)*256 + c4*4];
    }
    int src[7], cbase;
    if (IC){
      int tap = k0 >> 8;                    // 8-tile never crosses tap boundary
      int dy = tap/3 - 1, dx = tap - (tap/3)*3 - 1;
      int D = dy*9 + dx;
      cbase = k0 & 255;
      #pragma unroll
      for (int j=0;j<7;j++){
        int yy = pyv[j] + dy;
        src[j] = ((unsigned)yy < 7u) ? (rowb[j] + D) : 63;
      }
    } else {
      cbase = k0;
      #pragma unroll
      for (int j=0;j<7;j++) src[j] = rowb[j];
    }
    __syncthreads();
    #pragma unroll
    for (int kk=0; kk<8; kk++){
      float bv[4];
      #pragma unroll
      for (int qi=0;qi<4;qi++) bv[qi] = Bs[kk][cr + 32*(qh*4+qi)];
      #pragma unroll
      for (int j=0;j<7;j++){
        float av = As[src[j]][cbase+kk];
        #pragma unroll
        for (int qi=0;qi<4;qi++) acc[j][qi] = fmaf(av, bv[qi], acc[j][qi]);
      }
    }
    __syncthreads();   // all reads done before next Bs stage / writeback
  }

  float bb[4];
  #pragma unroll
  for (int qi=0;qi<4;qi++) bb[qi] = bias[cr + 32*(qh*4+qi)];
  #pragma unroll
  for (int j=0;j<7;j++){
    if (pr + 8*j < 49){
      #pragma unroll
      for (int qi=0;qi<4;qi++)
        As[rowb[j]][cr + 32*(qh*4+qi)] = relu_f(acc[j][qi] + bb[qi]);
    }
  }
  __syncthreads();
}

__global__ __launch_bounds__(512, 4) void k_fused_conv(
    const float* __restrict__ featT, const float* __restrict__ prop,
    const float* __restrict__ w11t, const float* __restrict__ b11,
    const float* __restrict__ w1t,  const float* __restrict__ b1,
    const float* __restrict__ w2t,  const float* __restrict__ b2,
    float* __restrict__ X3, int n0){
  __shared__ __align__(16) float As[64][256];   // 65536 B
  __shared__ __align__(16) float Bs[8][256];    // 8192 B  -> 73728 total (2 blk/CU)
  const int n = n0 + blockIdx.x;
  const int t = threadIdx.x;                    // 0..511
  const int b = (n >= 1000) ? 1 : 0;

  // zero all of As (pads + zero row); interior overwritten by ROI fill
  #pragma unroll
  for (int i = 0; i < 8; i++){
    float4 z; z.x = 0.f; z.y = 0.f; z.z = 0.f; z.w = 0.f;
    ((float4*)As)[t + i*512] = z;
  }
  __syncthreads();

  // ---- ROI align -> As[py*9+px+1][c] ----
  const float* pr4 = prop + n*4;
  float x = pr4[0], y = pr4[1], w = pr4[2], h = pr4[3];
  float x1 = x*0.03125f - 0.5f;
  float y1 = y*0.03125f - 0.5f;
  float x2 = (x+w)*0.03125f - 0.5f;
  float y2 = (y+h)*0.03125f - 0.5f;
  float bh = (y2 - y1) / 7.0f;
  float bw = (x2 - x1) / 7.0f;
  const float* fb = featT + (size_t)b*1024*256;
  for (int idx = t; idx < 12544; idx += 512){
    int p = idx >> 8;          // 0..48
    int c = idx & 255;
    int py = p / 7, px = p - py*7;
    float acc = 0.f;
    #pragma unroll
    for (int s = 0; s < 4; s++){
      int sy = s >> 1, sx = s & 1;
      float gy = (float)(py*2 + sy);
      float gx = (float)(px*2 + sx);
      float ys = y1 + ((gy + 0.5f) * bh) * 0.5f;
      float xs = x1 + ((gx + 0.5f) * bw) * 0.5f;
      bool valid = (ys > -1.0f) && (ys < 32.0f) && (xs > -1.0f) && (xs < 32.0f);
      float yc = fminf(fmaxf(ys, 0.f), 31.f);
      float xc = fminf(fmaxf(xs, 0.f), 31.f);
      int y0 = (int)floorf(yc), x0 = (int)floorf(xc);
      int y1i = min(y0+1, 31), x1i = min(x0+1, 31);
      float ly = yc - (float)y0, lx = xc - (float)x0;
      float hy = 1.f - ly, hx = 1.f - lx;
      const float* r0 = fb + (size_t)(y0*32)*256;
      const float* r1 = fb + (size_t)(y1i*32)*256;
      float f00 = r0[x0*256 + c],  f01 = r0[x1i*256 + c];
      float f10 = r1[x0*256 + c],  f11 = r1[x1i*256 + c];
      float v = f00*(hy*hx) + f01*(hy*lx) + f10*(ly*hx) + f11*(ly*lx);
      acc += valid ? v : 0.f;
    }
    As[py*9 + px + 1][c] = acc * 0.25f;
  }
  __syncthreads();

  conv_step<256, 0>(As, Bs, w11t, b11, t);
  conv_step<2304,1>(As, Bs, w1t,  b1,  t);
  conv_step<2304,1>(As, Bs, w2t,  b2,  t);

  // ---- write X3[e], e = co*49 + p (matches t.reshape(B,A,-1) order) ----
  #pragma unroll
  for (int i = 0; i < 25; i++){
    int e = i*512 + t;
    if (e < 12544){
      int co = e / 49, p = e - co*49;
      int py = p / 7, px = p - py*7;
      X3[(size_t)blockIdx.x*12544 + e] = As[py*9 + px + 1][co];
    }
  }
}

// ---------------- FC GEMM, B native [N][K]. BM=32 BN=128 BK=32 ----------------
// 256 threads = 8x32; thread (r,c) owns rows 4r..4r+3, cols 4c..4c+3.
__global__ __launch_bounds__(256) void k_gemm_fc_bt(const float* __restrict__ A,
    const float* __restrict__ Bt, const float* __restrict__ bias,
    float* __restrict__ C, int M, int K, int N){
  __shared__ __align__(16) float Ast[32][36];
  __shared__ __align__(16) float Bs[32][128];
  const int t = threadIdx.x;
  const int mt = blockIdx.x, nt = blockIdx.y;
  const int r = t >> 5, c = t & 31;
  float acc[4][4];
  #pragma unroll
  for (int i=0;i<4;i++){
    #pragma unroll
    for (int j=0;j<4;j++) acc[i][j] = 0.f;
  }

  for (int k0 = 0; k0 < K; k0 += 32){
    int gk = k0 + c;
    #pragma unroll
    for (int ms=0; ms<4; ms++){
      int ml = r + ms*8;
      int m = mt*32 + ml;
      Ast[c][ml] = (m < M) ? A[(size_t)m*K + gk] : 0.f;
    }
    #pragma unroll
    for (int it=0; it<4; it++){
      int fi = it*256 + t;               // 0..1023
      int nl = fi & 127, kq = fi >> 7;   // kq 0..7
      int nn = nt*128 + nl;
      float4 v = *(const float4*)&Bt[(size_t)nn*K + k0 + kq*4];
      Bs[kq*4+0][nl] = v.x; Bs[kq*4+1][nl] = v.y;
      Bs[kq*4+2][nl] = v.z; Bs[kq*4+3][nl] = v.w;
    }
    __syncthreads();
    #pragma unroll 8
    for (int kk=0; kk<32; kk++){
      float4 a  = *(const float4*)&Ast[kk][4*r];
      float4 b0 = *(const float4*)&Bs[kk][4*c];
      float av[4] = {a.x,a.y,a.z,a.w};
      float bv[4] = {b0.x,b0.y,b0.z,b0.w};
      #pragma unroll
      for (int i=0;i<4;i++){
        #pragma unroll
        for (int j=0;j<4;j++)
          acc[i][j] = fmaf(av[i], bv[j], acc[i][j]);
      }
    }
    __syncthreads();
  }

  float bv0[4];
  #pragma unroll
  for (int j=0;j<4;j++) bv0[j] = bias[nt*128 + 4*c + j];
  #pragma unroll
  for (int i=0;i<4;i++){
    int gr = mt*32 + 4*r + i;
    if (gr < M){
      float4 o0;
      o0.x = relu_f(acc[i][0]+bv0[0]); o0.y = relu_f(acc[i][1]+bv0[1]);
      o0.z = relu_f(acc[i][2]+bv0[2]); o0.w = relu_f(acc[i][3]+bv0[3]);
      *(float4*)&C[(size_t)gr*N + nt*128 + 4*c] = o0;
    }
  }
}

// ---------------- heads + box regression + clip ----------------
__global__ void k_head(const float* __restrict__ fc2, const float* __restrict__ wobj,
    const float* __restrict__ bobj, const float* __restrict__ wreg, const float* __restrict__ breg,
    const float* __restrict__ prop, float* __restrict__ out){
  int n = blockIdx.x, t = threadIdx.x;
  float s0=0.f, s1=0.f, s2=0.f, s3=0.f, s4=0.f;
  const float* v = fc2 + (size_t)n*1024;
  for (int i = t; i < 1024; i += 256){
    float x = v[i];
    s0 = fmaf(x, wobj[i], s0);
    s1 = fmaf(x, wreg[i], s1);
    s2 = fmaf(x, wreg[1024+i], s2);
    s3 = fmaf(x, wreg[2048+i], s3);
    s4 = fmaf(x, wreg[3072+i], s4);
  }
  #pragma unroll
  for (int off = 32; off >= 1; off >>= 1){
    s0 += __shfl_down(s0, off);
    s1 += __shfl_down(s1, off);
    s2 += __shfl_down(s2, off);
    s3 += __shfl_down(s3, off);
    s4 += __shfl_down(s4, off);
  }
  __shared__ float red[4][5];
  int w = t >> 6, lane = t & 63;
  if (lane == 0){ red[w][0]=s0; red[w][1]=s1; red[w][2]=s2; red[w][3]=s3; red[w][4]=s4; }
  __syncthreads();
  if (t == 0){
    float o0 = red[0][0]+red[1][0]+red[2][0]+red[3][0];
    float o1 = red[0][1]+red[1][1]+red[2][1]+red[3][1];
    float o2 = red[0][2]+red[1][2]+red[2][2]+red[3][2];
    float o3 = red[0][3]+red[1][3]+red[2][3]+red[3][3];
    float o4 = red[0][4]+red[1][4]+red[2][4]+red[3][4];
    float score = 1.f / (1.f + expf(-(o0 + bobj[0])));
    float d0 = (o1 + breg[0]) / 10.f;
    float d1 = (o2 + breg[1]) / 10.f;
    float d2 = (o3 + breg[2]) / 5.f;
    float d3 = (o4 + breg[3]) / 5.f;
    const float* pr = prop + n*4;
    float x = pr[0], y = pr[1], w0 = pr[2], h0 = pr[3];
    float cx = x + 0.5f*w0, cy = y + 0.5f*h0;
    float pw = w0 * expf(d2), ph = h0 * expf(d3);
    float pcx = d0*w0 + cx, pcy = d1*h0 + cy;
    float bx = pcx - 0.5f*pw, by = pcy - 0.5f*ph;
    float ox = fminf(fmaxf(bx, 0.f), 1024.f);
    float oy = fminf(fmaxf(by, 0.f), 1024.f);
    float ow = fminf(fmaxf(pw, 0.f), 1024.f - ox);
    float oh = fminf(fmaxf(ph, 0.f), 1024.f - oy);
    out[n*4+0] = ox; out[n*4+1] = oy; out[n*4+2] = ow; out[n*4+3] = oh;
    out[8000 + n] = score;
  }
}

// ---------------- NMS: stable sort (desc score, asc idx) ----------------
__global__ void k_sort(const float* __restrict__ dout, float* __restrict__ sbox,
                       int* __restrict__ order){
  int b = blockIdx.x, t = threadIdx.x;
  __shared__ u64 key[1024];
  const float* obj = dout + 8000;
  for (int i = t; i < 1024; i += 256){
    u64 k;
    if (i < 1000){
      unsigned bits = __float_as_uint(obj[b*1000+i]);  // sigmoid>0 -> uint order == float order
      k = ((u64)(~bits) << 32) | (unsigned)i;          // asc ~bits == desc score; ties asc idx
    } else {
      k = (0xFFFFFFFFull << 32) | (unsigned)i;
    }
    key[i] = k;
  }
  __syncthreads();
  for (int kk = 2; kk <= 1024; kk <<= 1){
    for (int j = kk >> 1; j > 0; j >>= 1){
      for (int i = t; i < 1024; i += 256){
        int ixj = i ^ j;
        if (ixj > i){
          u64 a = key[i], c2 = key[ixj];
          bool up = ((i & kk) == 0);
          if (up ? (a > c2) : (a < c2)){ key[i] = c2; key[ixj] = a; }
        }
      }
      __syncthreads();
    }
  }
  for (int i = t; i < 1000; i += 256){
    int idx = (int)(key[i] & 0xFFFFFFFFull);
    order[b*1000 + i] = idx;
    const float* bb = dout + (b*1000 + idx)*4;
    float xx = bb[0], yy = bb[1], ww = bb[2], hh = bb[3];
    float4 v; v.x = xx; v.y = yy; v.z = xx + ww; v.w = yy + hh;
    *(float4*)&sbox[(size_t)(b*1000 + i)*4] = v;
  }
}

__global__ void k_mask(const float* __restrict__ sbox, u64* __restrict__ mask){
  int i = blockIdx.x, b = blockIdx.y, t = threadIdx.x;
  float4 bi = *(const float4*)&sbox[(size_t)(b*1000 + i)*4];
  float areaI = fmaxf(bi.z - bi.x, 0.f) * fmaxf(bi.w - bi.y, 0.f);
  int w = t >> 6, lane = t & 63;
  #pragma unroll
  for (int cc = 0; cc < 4; cc++){
    int j = cc*256 + t;
    bool pred = false;
    if (j > i && j < 1000){
      float4 bj = *(const float4*)&sbox[(size_t)(b*1000 + j)*4];
      float areaJ = fmaxf(bj.z - bj.x, 0.f) * fmaxf(bj.w - bj.y, 0.f);
      float ix = fmaxf(bi.x, bj.x), iy = fmaxf(bi.y, bj.y);
      float ax = fminf(bi.z, bj.z), ay = fminf(bi.w, bj.w);
      float iw = fmaxf(ax - ix, 0.f), ih = fmaxf(ay - iy, 0.f);
      float inter = iw * ih;
      float iou = inter / fmaxf(areaI + areaJ - inter, 1e-9f);
      pred = iou > 0.5f;
    }
    u64 ball = __ballot((int)pred);
    if (lane == 0) mask[((size_t)(b*1000 + i))*16 + cc*4 + w] = ball;
  }
}

__global__ void k_scan(const u64* __restrict__ mask, const int* __restrict__ order,
                       const float* __restrict__ dout, float* __restrict__ outmask){
  int b = blockIdx.x, t = threadIdx.x;   // 64 threads
  u64 keepw = ~0ull;
  u64 nxt = (t < 16) ? mask[((size_t)(b*1000))*16 + t] : 0ull;
  for (int i = 0; i < 1000; i++){
    u64 cur = nxt;
    if (t < 16 && i + 1 < 1000) nxt = mask[((size_t)(b*1000 + i + 1))*16 + t];
    int w = i >> 6, bit = i & 63;
    u64 kw = __shfl(keepw, w);
    if ((kw >> bit) & 1ull) keepw &= ~cur;
  }
  __shared__ u64 kws[16];
  if (t < 16) kws[t] = keepw;
  __syncthreads();
  const float* obj = dout + 8000;
  for (int i = t; i < 1000; i += 64){
    int kbit = (int)((kws[i >> 6] >> (i & 63)) & 1ull);
    int orig = order[b*1000 + i];
    float sc = obj[b*1000 + orig];
    outmask[b*1000 + orig] = (kbit && sc > 0.05f) ? 1.0f : 0.0f;
  }
}

// ---------------- launch ----------------
extern "C" void kernel_launch(void* const* d_in, const int* in_sizes, int n_in,
                              void* d_out, int out_size, void* d_ws, size_t ws_size,
                              hipStream_t stream) {
  const float* feature = (const float*)d_in[0];
  const float* prop    = (const float*)d_in[1];
  const float* w11     = (const float*)d_in[2];
  const float* b11     = (const float*)d_in[3];
  const float* w1      = (const float*)d_in[4];
  const float* b1      = (const float*)d_in[5];
  const float* w2      = (const float*)d_in[6];
  const float* b2      = (const float*)d_in[7];
  const float* wf1     = (const float*)d_in[8];
  const float* bf1     = (const float*)d_in[9];
  const float* wf2     = (const float*)d_in[10];
  const float* bf2     = (const float*)d_in[11];
  const float* wobj    = (const float*)d_in[12];
  const float* bobj    = (const float*)d_in[13];
  const float* wreg    = (const float*)d_in[14];
  const float* breg    = (const float*)d_in[15];
  float* out = (float*)d_out;
  float* ws  = (float*)d_ws;

  // ---- ws layout (floats), X3 chunked to fit ws_size ----
  const size_t FIXEDF = 524288 + 65536 + 589824 + 589824 + 2048000 + 2048000
                      + 8000 + 2000 + 64000;   // 5,939,472 floats
  static const int cand[] = {2000, 1000, 500, 250, 125, 64, 32, 16, 8, 4, 2, 1};
  int chunk = 1;
  for (int ci = 0; ci < 12; ci++){
    size_t need = (FIXEDF + (size_t)cand[ci]*12544) * 4;
    if (need <= ws_size){ chunk = cand[ci]; break; }
  }

  float* featT = ws;                         // 524288
  float* w11t  = featT + 524288;             // 65536
  float* w1t   = w11t + 65536;               // 589824
  float* w2t   = w1t + 589824;               // 589824
  float* fc1   = w2t + 589824;               // 2048000
  float* fc2   = fc1 + 2048000;              // 2048000
  float* sbox  = fc2 + 2048000;              // 8000
  int*   order = (int*)(sbox + 8000);        // 2000
  u64*   maskp = (u64*)(sbox + 10000);       // 32000 u64 (64000 floats)
  float* X3c   = sbox + 74000;               // chunk*12544

  k_feat_t<<<2048, 256, 0, stream>>>(feature, featT);
  k_w11t  <<<256,  256, 0, stream>>>(w11, w11t);
  k_w33t  <<<2304, 256, 0, stream>>>(w1, w1t);
  k_w33t  <<<2304, 256, 0, stream>>>(w2, w2t);

  for (int n0 = 0; n0 < 2000; n0 += chunk){
    int cnt = (2000 - n0 < chunk) ? (2000 - n0) : chunk;
    k_fused_conv<<<cnt, 512, 0, stream>>>(featT, prop, w11t, b11, w1t, b1, w2t, b2,
                                          X3c, n0);
    k_gemm_fc_bt<<<dim3((cnt + 31)/32, 8), 256, 0, stream>>>(
        X3c, wf1, bf1, fc1 + (size_t)n0*1024, cnt, 12544, 1024);
  }

  k_gemm_fc_bt<<<dim3(63, 8), 256, 0, stream>>>(fc1, wf2, bf2, fc2, 2000, 1024, 1024);

  k_head<<<2000, 256, 0, stream>>>(fc2, wobj, bobj, wreg, breg, prop, out);

  k_sort<<<2, 256, 0, stream>>>(out, sbox, order);
  k_mask<<<dim3(1000, 2), 256, 0, stream>>>(sbox, maskp);
  k_scan<<<2, 64, 0, stream>>>(maskp, order, out, out + 10000);
}

// Round 9
// 5493.972 us; speedup vs baseline: 1.4113x; 1.1161x over previous
//
#include <hip/hip_runtime.h>
#include <cstdint>
#include <cstddef>

typedef unsigned long long u64;

// B=2, A=1000, C=256, R=7, P=49, FC=1024, K_fc1=12544
// out (fp32): [0,8000) bboxes xywh | [8000,10000) objectness | [10000,12000) mask

__device__ __forceinline__ float relu_f(float v){ return fmaxf(v, 0.f); }

// ---------------- transposes ----------------
__global__ void k_feat_t(const float* __restrict__ in, float* __restrict__ out){
  int bp = blockIdx.x;           // b*1024 + yx
  int c  = threadIdx.x;          // 256
  int b  = bp >> 10, yx = bp & 1023;
  out[(size_t)bp*256 + c] = in[((size_t)(b*256 + c))*1024 + yx];
}

__global__ void k_w11t(const float* __restrict__ in, float* __restrict__ out){
  int e = blockIdx.x*256 + threadIdx.x;   // ci*256+co
  int co = e & 255, ci = e >> 8;
  out[e] = in[co*256 + ci];
}

__global__ void k_w33t(const float* __restrict__ in, float* __restrict__ out){
  int e = blockIdx.x*256 + threadIdx.x;   // (tap*256+ci)*256+co
  int co = e & 255;
  int k  = e >> 8;
  int ci = k & 255, tap = k >> 8;
  out[e] = in[(size_t)(co*256 + ci)*9 + tap];
}

// ---------------- fused per-ROI conv chain ----------------
// As[64][256], interior row = py*9+px+1, x-pads zeroed, row 63 = zero row.
// Thread map: cg = t&63 (cols co = cg*4..cg*4+3), pr = t>>6 == wave id (rows p = pr+8j).
// -> As reads are wave-uniform b128 BROADCASTS (free); Bs reads/As writes are
//    canonical contiguous-1024B b128 (conflict-free). 22 b128-req + 224 FMA per k-tile.
template<int K, int IC>
__device__ __forceinline__ void conv_step(float (&As)[64][256], float (&Bs)[8][256],
    const float* __restrict__ Bw, const float* __restrict__ bias, int t){
  const int cg = t & 63;          // col group
  const int pr = t >> 6;          // wave id = row group

  int pyv[7], rowb[7];
  #pragma unroll
  for (int j = 0; j < 7; j++){
    int p = pr + 8*j;
    int pyj = p / 7, pxj = p - pyj*7;
    bool v = (p < 49);
    pyv[j]  = v ? pyj : 99;
    rowb[j] = v ? (pyj*9 + pxj + 1) : 63;
  }

  float acc[7][4];
  #pragma unroll
  for (int j=0;j<7;j++){
    #pragma unroll
    for (int q=0;q<4;q++) acc[j][q] = 0.f;
  }

  for (int k0 = 0; k0 < K; k0 += 8){
    // stage Bs[8][256] <- Bw[k0..k0+8)[256] : 512 thr x 1 float4
    {
      int krow = t >> 6;          // 0..7
      int c4 = t & 63;            // 0..63
      *(float4*)&Bs[krow][c4*4] = *(const float4*)&Bw[(size_t)(k0+krow)*256 + c4*4];
    }
    int src[7], cbase;
    if (IC){
      int tap = k0 >> 8;                    // 8-tile never crosses tap boundary
      int dy = tap/3 - 1, dx = tap - (tap/3)*3 - 1;
      int D = dy*9 + dx;
      cbase = k0 & 255;
      #pragma unroll
      for (int j=0;j<7;j++){
        int yy = pyv[j] + dy;
        src[j] = ((unsigned)yy < 7u) ? (rowb[j] + D) : 63;
      }
    } else {
      cbase = k0;
      #pragma unroll
      for (int j=0;j<7;j++) src[j] = rowb[j];
    }
    __syncthreads();
    #pragma unroll
    for (int h = 0; h < 2; h++){            // two 4-kk halves
      float4 a[7];
      #pragma unroll
      for (int j=0;j<7;j++) a[j] = *(const float4*)&As[src[j]][cbase + 4*h];  // broadcast
      float4 bq[4];
      #pragma unroll
      for (int kk=0;kk<4;kk++) bq[kk] = *(const float4*)&Bs[4*h + kk][cg*4];  // contiguous
      #pragma unroll
      for (int kk=0;kk<4;kk++){
        float av[4] = {a[0][kk], a[1][kk], a[2][kk], a[3][kk]};
        #pragma unroll
        for (int j=0;j<7;j++){
          float aj = (&a[0])[j][kk];
          acc[j][0] = fmaf(aj, bq[kk].x, acc[j][0]);
          acc[j][1] = fmaf(aj, bq[kk].y, acc[j][1]);
          acc[j][2] = fmaf(aj, bq[kk].z, acc[j][2]);
          acc[j][3] = fmaf(aj, bq[kk].w, acc[j][3]);
        }
        (void)av;
      }
    }
    __syncthreads();   // all reads done before next Bs stage / writeback
  }

  float4 bb = *(const float4*)&bias[cg*4];
  #pragma unroll
  for (int j=0;j<7;j++){
    if (pr + 8*j < 49){
      float4 o;
      o.x = relu_f(acc[j][0] + bb.x);
      o.y = relu_f(acc[j][1] + bb.y);
      o.z = relu_f(acc[j][2] + bb.z);
      o.w = relu_f(acc[j][3] + bb.w);
      *(float4*)&As[rowb[j]][cg*4] = o;     // whole wave writes one 1024B row
    }
  }
  __syncthreads();
}

__global__ __launch_bounds__(512, 4) void k_fused_conv(
    const float* __restrict__ featT, const float* __restrict__ prop,
    const float* __restrict__ w11t, const float* __restrict__ b11,
    const float* __restrict__ w1t,  const float* __restrict__ b1,
    const float* __restrict__ w2t,  const float* __restrict__ b2,
    float* __restrict__ X3, int n0){
  __shared__ __align__(16) float As[64][256];   // 65536 B
  __shared__ __align__(16) float Bs[8][256];    // 8192 B  -> 73728 total (2 blk/CU)
  const int n = n0 + blockIdx.x;
  const int t = threadIdx.x;                    // 0..511
  const int b = (n >= 1000) ? 1 : 0;

  // zero all of As (pads + zero row); interior overwritten by ROI fill
  #pragma unroll
  for (int i = 0; i < 8; i++){
    float4 z; z.x = 0.f; z.y = 0.f; z.z = 0.f; z.w = 0.f;
    ((float4*)As)[t + i*512] = z;
  }
  __syncthreads();

  // ---- ROI align -> As[py*9+px+1][c] ----
  const float* pr4 = prop + n*4;
  float x = pr4[0], y = pr4[1], w = pr4[2], h = pr4[3];
  float x1 = x*0.03125f - 0.5f;
  float y1 = y*0.03125f - 0.5f;
  float x2 = (x+w)*0.03125f - 0.5f;
  float y2 = (y+h)*0.03125f - 0.5f;
  float bh = (y2 - y1) / 7.0f;
  float bw = (x2 - x1) / 7.0f;
  const float* fb = featT + (size_t)b*1024*256;
  for (int idx = t; idx < 12544; idx += 512){
    int p = idx >> 8;          // 0..48
    int c = idx & 255;
    int py = p / 7, px = p - py*7;
    float acc = 0.f;
    #pragma unroll
    for (int s = 0; s < 4; s++){
      int sy = s >> 1, sx = s & 1;
      float gy = (float)(py*2 + sy);
      float gx = (float)(px*2 + sx);
      float ys = y1 + ((gy + 0.5f) * bh) * 0.5f;
      float xs = x1 + ((gx + 0.5f) * bw) * 0.5f;
      bool valid = (ys > -1.0f) && (ys < 32.0f) && (xs > -1.0f) && (xs < 32.0f);
      float yc = fminf(fmaxf(ys, 0.f), 31.f);
      float xc = fminf(fmaxf(xs, 0.f), 31.f);
      int y0 = (int)floorf(yc), x0 = (int)floorf(xc);
      int y1i = min(y0+1, 31), x1i = min(x0+1, 31);
      float ly = yc - (float)y0, lx = xc - (float)x0;
      float hy = 1.f - ly, hx = 1.f - lx;
      const float* r0 = fb + (size_t)(y0*32)*256;
      const float* r1 = fb + (size_t)(y1i*32)*256;
      float f00 = r0[x0*256 + c],  f01 = r0[x1i*256 + c];
      float f10 = r1[x0*256 + c],  f11 = r1[x1i*256 + c];
      float v = f00*(hy*hx) + f01*(hy*lx) + f10*(ly*hx) + f11*(ly*lx);
      acc += valid ? v : 0.f;
    }
    As[py*9 + px + 1][c] = acc * 0.25f;
  }
  __syncthreads();

  conv_step<256, 0>(As, Bs, w11t, b11, t);
  conv_step<2304,1>(As, Bs, w1t,  b1,  t);
  conv_step<2304,1>(As, Bs, w2t,  b2,  t);

  // ---- write X3[e], e = co*49 + p (matches t.reshape(B,A,-1) order) ----
  #pragma unroll
  for (int i = 0; i < 25; i++){
    int e = i*512 + t;
    if (e < 12544){
      int co = e / 49, p = e - co*49;
      int py = p / 7, px = p - py*7;
      X3[(size_t)blockIdx.x*12544 + e] = As[py*9 + px + 1][co];
    }
  }
}

// ---------------- FC GEMM, B native [N][K]. BM=32 BN=128 BK=32 ----------------
// 256 threads = 8x32; thread (r,c) owns rows 4r..4r+3, cols 4c..4c+3.
__global__ __launch_bounds__(256) void k_gemm_fc_bt(const float* __restrict__ A,
    const float* __restrict__ Bt, const float* __restrict__ bias,
    float* __restrict__ C, int M, int K, int N){
  __shared__ __align__(16) float Ast[32][36];
  __shared__ __align__(16) float Bs[32][128];
  const int t = threadIdx.x;
  const int mt = blockIdx.x, nt = blockIdx.y;
  const int r = t >> 5, c = t & 31;
  float acc[4][4];
  #pragma unroll
  for (int i=0;i<4;i++){
    #pragma unroll
    for (int j=0;j<4;j++) acc[i][j] = 0.f;
  }

  for (int k0 = 0; k0 < K; k0 += 32){
    int gk = k0 + c;
    #pragma unroll
    for (int ms=0; ms<4; ms++){
      int ml = r + ms*8;
      int m = mt*32 + ml;
      Ast[c][ml] = (m < M) ? A[(size_t)m*K + gk] : 0.f;
    }
    #pragma unroll
    for (int it=0; it<4; it++){
      int fi = it*256 + t;               // 0..1023
      int nl = fi & 127, kq = fi >> 7;   // kq 0..7
      int nn = nt*128 + nl;
      float4 v = *(const float4*)&Bt[(size_t)nn*K + k0 + kq*4];
      Bs[kq*4+0][nl] = v.x; Bs[kq*4+1][nl] = v.y;
      Bs[kq*4+2][nl] = v.z; Bs[kq*4+3][nl] = v.w;
    }
    __syncthreads();
    #pragma unroll 8
    for (int kk=0; kk<32; kk++){
      float4 a  = *(const float4*)&Ast[kk][4*r];
      float4 b0 = *(const float4*)&Bs[kk][4*c];
      float av[4] = {a.x,a.y,a.z,a.w};
      float bv[4] = {b0.x,b0.y,b0.z,b0.w};
      #pragma unroll
      for (int i=0;i<4;i++){
        #pragma unroll
        for (int j=0;j<4;j++)
          acc[i][j] = fmaf(av[i], bv[j], acc[i][j]);
      }
    }
    __syncthreads();
  }

  float bv0[4];
  #pragma unroll
  for (int j=0;j<4;j++) bv0[j] = bias[nt*128 + 4*c + j];
  #pragma unroll
  for (int i=0;i<4;i++){
    int gr = mt*32 + 4*r + i;
    if (gr < M){
      float4 o0;
      o0.x = relu_f(acc[i][0]+bv0[0]); o0.y = relu_f(acc[i][1]+bv0[1]);
      o0.z = relu_f(acc[i][2]+bv0[2]); o0.w = relu_f(acc[i][3]+bv0[3]);
      *(float4*)&C[(size_t)gr*N + nt*128 + 4*c] = o0;
    }
  }
}

// ---------------- heads + box regression + clip ----------------
__global__ void k_head(const float* __restrict__ fc2, const float* __restrict__ wobj,
    const float* __restrict__ bobj, const float* __restrict__ wreg, const float* __restrict__ breg,
    const float* __restrict__ prop, float* __restrict__ out){
  int n = blockIdx.x, t = threadIdx.x;
  float s0=0.f, s1=0.f, s2=0.f, s3=0.f, s4=0.f;
  const float* v = fc2 + (size_t)n*1024;
  for (int i = t; i < 1024; i += 256){
    float x = v[i];
    s0 = fmaf(x, wobj[i], s0);
    s1 = fmaf(x, wreg[i], s1);
    s2 = fmaf(x, wreg[1024+i], s2);
    s3 = fmaf(x, wreg[2048+i], s3);
    s4 = fmaf(x, wreg[3072+i], s4);
  }
  #pragma unroll
  for (int off = 32; off >= 1; off >>= 1){
    s0 += __shfl_down(s0, off);
    s1 += __shfl_down(s1, off);
    s2 += __shfl_down(s2, off);
    s3 += __shfl_down(s3, off);
    s4 += __shfl_down(s4, off);
  }
  __shared__ float red[4][5];
  int w = t >> 6, lane = t & 63;
  if (lane == 0){ red[w][0]=s0; red[w][1]=s1; red[w][2]=s2; red[w][3]=s3; red[w][4]=s4; }
  __syncthreads();
  if (t == 0){
    float o0 = red[0][0]+red[1][0]+red[2][0]+red[3][0];
    float o1 = red[0][1]+red[1][1]+red[2][1]+red[3][1];
    float o2 = red[0][2]+red[1][2]+red[2][2]+red[3][2];
    float o3 = red[0][3]+red[1][3]+red[2][3]+red[3][3];
    float o4 = red[0][4]+red[1][4]+red[2][4]+red[3][4];
    float score = 1.f / (1.f + expf(-(o0 + bobj[0])));
    float d0 = (o1 + breg[0]) / 10.f;
    float d1 = (o2 + breg[1]) / 10.f;
    float d2 = (o3 + breg[2]) / 5.f;
    float d3 = (o4 + breg[3]) / 5.f;
    const float* pr = prop + n*4;
    float x = pr[0], y = pr[1], w0 = pr[2], h0 = pr[3];
    float cx = x + 0.5f*w0, cy = y + 0.5f*h0;
    float pw = w0 * expf(d2), ph = h0 * expf(d3);
    float pcx = d0*w0 + cx, pcy = d1*h0 + cy;
    float bx = pcx - 0.5f*pw, by = pcy - 0.5f*ph;
    float ox = fminf(fmaxf(bx, 0.f), 1024.f);
    float oy = fminf(fmaxf(by, 0.f), 1024.f);
    float ow = fminf(fmaxf(pw, 0.f), 1024.f - ox);
    float oh = fminf(fmaxf(ph, 0.f), 1024.f - oy);
    out[n*4+0] = ox; out[n*4+1] = oy; out[n*4+2] = ow; out[n*4+3] = oh;
    out[8000 + n] = score;
  }
}

// ---------------- NMS: stable sort (desc score, asc idx) ----------------
__global__ void k_sort(const float* __restrict__ dout, float* __restrict__ sbox,
                       int* __restrict__ order){
  int b = blockIdx.x, t = threadIdx.x;
  __shared__ u64 key[1024];
  const float* obj = dout + 8000;
  for (int i = t; i < 1024; i += 256){
    u64 k;
    if (i < 1000){
      unsigned bits = __float_as_uint(obj[b*1000+i]);  // sigmoid>0 -> uint order == float order
      k = ((u64)(~bits) << 32) | (unsigned)i;          // asc ~bits == desc score; ties asc idx
    } else {
      k = (0xFFFFFFFFull << 32) | (unsigned)i;
    }
    key[i] = k;
  }
  __syncthreads();
  for (int kk = 2; kk <= 1024; kk <<= 1){
    for (int j = kk >> 1; j > 0; j >>= 1){
      for (int i = t; i < 1024; i += 256){
        int ixj = i ^ j;
        if (ixj > i){
          u64 a = key[i], c2 = key[ixj];
          bool up = ((i & kk) == 0);
          if (up ? (a > c2) : (a < c2)){ key[i] = c2; key[ixj] = a; }
        }
      }
      __syncthreads();
    }
  }
  for (int i = t; i < 1000; i += 256){
    int idx = (int)(key[i] & 0xFFFFFFFFull);
    order[b*1000 + i] = idx;
    const float* bb = dout + (b*1000 + idx)*4;
    float xx = bb[0], yy = bb[1], ww = bb[2], hh = bb[3];
    float4 v; v.x = xx; v.y = yy; v.z = xx + ww; v.w = yy + hh;
    *(float4*)&sbox[(size_t)(b*1000 + i)*4] = v;
  }
}

__global__ void k_mask(const float* __restrict__ sbox, u64* __restrict__ mask){
  int i = blockIdx.x, b = blockIdx.y, t = threadIdx.x;
  float4 bi = *(const float4*)&sbox[(size_t)(b*1000 + i)*4];
  float areaI = fmaxf(bi.z - bi.x, 0.f) * fmaxf(bi.w - bi.y, 0.f);
  int w = t >> 6, lane = t & 63;
  #pragma unroll
  for (int cc = 0; cc < 4; cc++){
    int j = cc*256 + t;
    bool pred = false;
    if (j > i && j < 1000){
      float4 bj = *(const float4*)&sbox[(size_t)(b*1000 + j)*4];
      float areaJ = fmaxf(bj.z - bj.x, 0.f) * fmaxf(bj.w - bj.y, 0.f);
      float ix = fmaxf(bi.x, bj.x), iy = fmaxf(bi.y, bj.y);
      float ax = fminf(bi.z, bj.z), ay = fminf(bi.w, bj.w);
      float iw = fmaxf(ax - ix, 0.f), ih = fmaxf(ay - iy, 0.f);
      float inter = iw * ih;
      float iou = inter / fmaxf(areaI + areaJ - inter, 1e-9f);
      pred = iou > 0.5f;
    }
    u64 ball = __ballot((int)pred);
    if (lane == 0) mask[((size_t)(b*1000 + i))*16 + cc*4 + w] = ball;
  }
}

__global__ void k_scan(const u64* __restrict__ mask, const int* __restrict__ order,
                       const float* __restrict__ dout, float* __restrict__ outmask){
  int b = blockIdx.x, t = threadIdx.x;   // 64 threads
  u64 keepw = ~0ull;
  u64 nxt = (t < 16) ? mask[((size_t)(b*1000))*16 + t] : 0ull;
  for (int i = 0; i < 1000; i++){
    u64 cur = nxt;
    if (t < 16 && i + 1 < 1000) nxt = mask[((size_t)(b*1000 + i + 1))*16 + t];
    int w = i >> 6, bit = i & 63;
    u64 kw = __shfl(keepw, w);
    if ((kw >> bit) & 1ull) keepw &= ~cur;
  }
  __shared__ u64 kws[16];
  if (t < 16) kws[t] = keepw;
  __syncthreads();
  const float* obj = dout + 8000;
  for (int i = t; i < 1000; i += 64){
    int kbit = (int)((kws[i >> 6] >> (i & 63)) & 1ull);
    int orig = order[b*1000 + i];
    float sc = obj[b*1000 + orig];
    outmask[b*1000 + orig] = (kbit && sc > 0.05f) ? 1.0f : 0.0f;
  }
}

// ---------------- launch ----------------
extern "C" void kernel_launch(void* const* d_in, const int* in_sizes, int n_in,
                              void* d_out, int out_size, void* d_ws, size_t ws_size,
                              hipStream_t stream) {
  const float* feature = (const float*)d_in[0];
  const float* prop    = (const float*)d_in[1];
  const float* w11     = (const float*)d_in[2];
  const float* b11     = (const float*)d_in[3];
  const float* w1      = (const float*)d_in[4];
  const float* b1      = (const float*)d_in[5];
  const float* w2      = (const float*)d_in[6];
  const float* b2      = (const float*)d_in[7];
  const float* wf1     = (const float*)d_in[8];
  const float* bf1     = (const float*)d_in[9];
  const float* wf2     = (const float*)d_in[10];
  const float* bf2     = (const float*)d_in[11];
  const float* wobj    = (const float*)d_in[12];
  const float* bobj    = (const float*)d_in[13];
  const float* wreg    = (const float*)d_in[14];
  const float* breg    = (const float*)d_in[15];
  float* out = (float*)d_out;
  float* ws  = (float*)d_ws;

  // ---- ws layout (floats), X3 chunked to fit ws_size ----
  const size_t FIXEDF = 524288 + 65536 + 589824 + 589824 + 2048000 + 2048000
                      + 8000 + 2000 + 64000;   // 5,939,472 floats
  static const int cand[] = {2000, 1000, 500, 250, 125, 64, 32, 16, 8, 4, 2, 1};
  int chunk = 1;
  for (int ci = 0; ci < 12; ci++){
    size_t need = (FIXEDF + (size_t)cand[ci]*12544) * 4;
    if (need <= ws_size){ chunk = cand[ci]; break; }
  }

  float* featT = ws;                         // 524288
  float* w11t  = featT + 524288;             // 65536
  float* w1t   = w11t + 65536;               // 589824
  float* w2t   = w1t + 589824;               // 589824
  float* fc1   = w2t + 589824;               // 2048000
  float* fc2   = fc1 + 2048000;              // 2048000
  float* sbox  = fc2 + 2048000;              // 8000
  int*   order = (int*)(sbox + 8000);        // 2000
  u64*   maskp = (u64*)(sbox + 10000);       // 32000 u64 (64000 floats)
  float* X3c   = sbox + 74000;               // chunk*12544

  k_feat_t<<<2048, 256, 0, stream>>>(feature, featT);
  k_w11t  <<<256,  256, 0, stream>>>(w11, w11t);
  k_w33t  <<<2304, 256, 0, stream>>>(w1, w1t);
  k_w33t  <<<2304, 256, 0, stream>>>(w2, w2t);

  for (int n0 = 0; n0 < 2000; n0 += chunk){
    int cnt = (2000 - n0 < chunk) ? (2000 - n0) : chunk;
    k_fused_conv<<<cnt, 512, 0, stream>>>(featT, prop, w11t, b11, w1t, b1, w2t, b2,
                                          X3c, n0);
    k_gemm_fc_bt<<<dim3((cnt + 31)/32, 8), 256, 0, stream>>>(
        X3c, wf1, bf1, fc1 + (size_t)n0*1024, cnt, 12544, 1024);
  }

  k_gemm_fc_bt<<<dim3(63, 8), 256, 0, stream>>>(fc1, wf2, bf2, fc2, 2000, 1024, 1024);

  k_head<<<2000, 256, 0, stream>>>(fc2, wobj, bobj, wreg, breg, prop, out);

  k_sort<<<2, 256, 0, stream>>>(out, sbox, order);
  k_mask<<<dim3(1000, 2), 256, 0, stream>>>(sbox, maskp);
  k_scan<<<2, 64, 0, stream>>>(maskp, order, out, out + 10000);
}